// Round 2
// baseline (5652.187 us; speedup 1.0000x reference)
//
#include <hip/hip_runtime.h>
#include <math.h>

#define LAYERS 2
#define NNEI 120
#define ED 64
#define HD 128
#define NB 4096
#define F3 (3*HD)
#define SCALING 0.088388347648318447f
#define LN_EPS 1e-5f
#define T 512
#define XPAD 68
#define QPAD 136

typedef unsigned short u16;
typedef unsigned int u32;
typedef unsigned char u8;

__device__ __forceinline__ float bf2f(u16 u) { return __uint_as_float(((u32)u) << 16); }
__device__ __forceinline__ float blo(u32 u) { return __uint_as_float(u << 16); }
__device__ __forceinline__ float bhi(u32 u) { return __uint_as_float(u & 0xffff0000u); }
__device__ __forceinline__ u16 f2bf(float f) {
  u32 i = __float_as_uint(f);
  u32 r = (i + 0x7fffu + ((i >> 16) & 1u)) >> 16;   // RNE
  return (u16)r;
}

// dtype-generic global loads
template<bool F32>
__device__ __forceinline__ float gld(const void* p, long i) {
  if constexpr (F32) return ((const float*)p)[i];
  else               return bf2f(((const u16*)p)[i]);
}
template<bool MBYTE>
__device__ __forceinline__ int mld(const void* p, long i) {
  if constexpr (MBYTE) return (int)((const u8*)p)[i];
  else                 return ((const int*)p)[i];
}

// ---- detector: flags[0]=1 if float inputs are f32 (not bf16);
//                flags[1]=1 if mask is byte-encoded (not int32) ----
__global__ void detect_kernel(const u16* __restrict__ G,
                              const u8* __restrict__ mask,
                              int* __restrict__ flags) {
  if (threadIdx.x == 0 && blockIdx.x == 0) {
    int isf32 = 0;
    for (int i = 0; i < 256; ++i) {
      // even u16 index: for f32 data this is a random mantissa word
      int e = (G[2 * i] >> 7) & 0xff;
      if (e >= 150) { isf32 = 1; break; }
    }
    int mbyte = 0;
    for (int i = 1; i < 4096; ++i) {
      if ((i & 3) && mask[i]) { mbyte = 1; break; }
    }
    flags[0] = isf32;
    flags[1] = mbyte;
  }
}

template<bool F32, bool MBYTE>
__global__ __launch_bounds__(T, 2) void nwa_kernel(
    const void* __restrict__ G, const void* __restrict__ mask,
    const void* __restrict__ rr, const void* __restrict__ in_w,
    const void* __restrict__ in_b, const void* __restrict__ out_w,
    const void* __restrict__ out_b, const void* __restrict__ ln_g,
    const void* __restrict__ ln_b, void* __restrict__ out,
    const int* __restrict__ flags)
{
  if (((flags[0] != 0) != F32) || ((flags[1] != 0) != MBYTE)) return;

  __shared__ __align__(16) float x_s[NNEI][XPAD];   // f32 current x / residual
  __shared__ __align__(16) u16 q_s[NNEI][QPAD];     // q (later reused for o)
  __shared__ __align__(16) u16 k_s[NNEI][QPAD];     // k
  __shared__ __align__(16) u16 vT_s[HD][QPAD];      // v transposed: [h][m]
  __shared__ __align__(16) float r_s[NNEI][4];
  __shared__ int m_s[NNEI];
  __shared__ __align__(16) float aw_s[8][128];      // per-wave attention row

  const int b = blockIdx.x;
  const int t = threadIdx.x;
  const int wave = t >> 6;
  const int lane = t & 63;

  // ---- load x, r, mask ----
  {
    const long gbase = (long)b * (NNEI * ED);
    for (int i = t; i < NNEI * ED; i += T)
      x_s[i >> 6][i & 63] = gld<F32>(G, gbase + i);
    const long rbase = (long)b * (NNEI * 3);
    const long mbase = (long)b * NNEI;
    for (int i = t; i < NNEI; i += T) {
      r_s[i][0] = gld<F32>(rr, rbase + i * 3 + 0);
      r_s[i][1] = gld<F32>(rr, rbase + i * 3 + 1);
      r_s[i][2] = gld<F32>(rr, rbase + i * 3 + 2);
      r_s[i][3] = 0.f;
      m_s[i] = mld<MBYTE>(mask, mbase + i);
    }
  }
  __syncthreads();

  for (int l = 0; l < LAYERS; ++l) {
    const long wbase = (long)l * (ED * F3);
    const long bbase = (long)l * F3;

    // ---- phase 1: qkv = x @ in_w + in_b  (4-way n-blocked) ----
    for (int idx = t; idx < 30 * F3; idx += T) {
      const int n0 = idx / F3;
      const int f = idx % F3;
      const float bias = gld<F32>(in_b, bbase + f);
      float a0 = bias, a1 = bias, a2 = bias, a3 = bias;
      const long wcol = wbase + f;
      for (int e = 0; e < ED; e += 4) {
        const float4 xa = *(const float4*)&x_s[n0][e];
        const float4 xb = *(const float4*)&x_s[n0 + 30][e];
        const float4 xc = *(const float4*)&x_s[n0 + 60][e];
        const float4 xd = *(const float4*)&x_s[n0 + 90][e];
        const float w0 = gld<F32>(in_w, wcol + (long)(e + 0) * F3);
        const float w1 = gld<F32>(in_w, wcol + (long)(e + 1) * F3);
        const float w2 = gld<F32>(in_w, wcol + (long)(e + 2) * F3);
        const float w3 = gld<F32>(in_w, wcol + (long)(e + 3) * F3);
        a0 += xa.x * w0 + xa.y * w1 + xa.z * w2 + xa.w * w3;
        a1 += xb.x * w0 + xb.y * w1 + xb.z * w2 + xb.w * w3;
        a2 += xc.x * w0 + xc.y * w1 + xc.z * w2 + xc.w * w3;
        a3 += xd.x * w0 + xd.y * w1 + xd.z * w2 + xd.w * w3;
      }
      const int which = f >> 7;
      const int h = f & 127;
      if (which == 0) {
        q_s[n0][h] = f2bf(a0); q_s[n0 + 30][h] = f2bf(a1);
        q_s[n0 + 60][h] = f2bf(a2); q_s[n0 + 90][h] = f2bf(a3);
      } else if (which == 1) {
        k_s[n0][h] = f2bf(a0); k_s[n0 + 30][h] = f2bf(a1);
        k_s[n0 + 60][h] = f2bf(a2); k_s[n0 + 90][h] = f2bf(a3);
      } else {
        vT_s[h][n0] = f2bf(a0); vT_s[h][n0 + 30] = f2bf(a1);
        vT_s[h][n0 + 60] = f2bf(a2); vT_s[h][n0 + 90] = f2bf(a3);
      }
    }
    __syncthreads();

    // ---- phase 2: l2-normalize q, k, v rows ----
    for (int rw = t; rw < 3 * NNEI; rw += T) {
      const int which = rw / NNEI;
      const int n = rw % NNEI;
      if (which < 2) {
        u16* row = (which == 0) ? &q_s[n][0] : &k_s[n][0];
        float ss = 0.f;
        for (int h = 0; h < HD; h += 8) {
          const uint4 a = *(const uint4*)(row + h);
          float f0 = blo(a.x), f1 = bhi(a.x), f2 = blo(a.y), f3 = bhi(a.y);
          float f4 = blo(a.z), f5 = bhi(a.z), f6 = blo(a.w), f7 = bhi(a.w);
          ss += f0*f0 + f1*f1 + f2*f2 + f3*f3 + f4*f4 + f5*f5 + f6*f6 + f7*f7;
        }
        float inv = 1.f / fmaxf(sqrtf(ss), 1e-12f);
        if (which == 0) inv *= SCALING;
        for (int h = 0; h < HD; h += 2) {
          u32 u = *(u32*)(row + h);
          u32 lo = f2bf(blo(u) * inv);
          u32 hi = f2bf(bhi(u) * inv);
          *(u32*)(row + h) = lo | (hi << 16);
        }
      } else {
        float ss = 0.f;
        for (int h = 0; h < HD; ++h) { float x = bf2f(vT_s[h][n]); ss += x * x; }
        float inv = 1.f / fmaxf(sqrtf(ss), 1e-12f);
        for (int h = 0; h < HD; ++h) vT_s[h][n] = f2bf(bf2f(vT_s[h][n]) * inv);
      }
    }
    __syncthreads();

    // ---- phase 3: attention, one q-row per wave per iteration ----
    for (int it = 0; it < 15; ++it) {
      const int n = wave + (it << 3);
      const int m1i = (lane < 56) ? (lane + 64) : 0;  // second key index (clamped)
      float acc0 = 0.f, acc1 = 0.f;
      {
        const u16* qrow = &q_s[n][0];
        const u16* k0 = &k_s[lane][0];
        const u16* k1 = &k_s[m1i][0];
        for (int h = 0; h < HD; h += 8) {
          const uint4 qa = *(const uint4*)(qrow + h);
          const uint4 ka = *(const uint4*)(k0 + h);
          const uint4 kb = *(const uint4*)(k1 + h);
          acc0 += blo(qa.x)*blo(ka.x) + bhi(qa.x)*bhi(ka.x)
               +  blo(qa.y)*blo(ka.y) + bhi(qa.y)*bhi(ka.y)
               +  blo(qa.z)*blo(ka.z) + bhi(qa.z)*bhi(ka.z)
               +  blo(qa.w)*blo(ka.w) + bhi(qa.w)*bhi(ka.w);
          acc1 += blo(qa.x)*blo(kb.x) + bhi(qa.x)*bhi(kb.x)
               +  blo(qa.y)*blo(kb.y) + bhi(qa.y)*bhi(kb.y)
               +  blo(qa.z)*blo(kb.z) + bhi(qa.z)*bhi(kb.z)
               +  blo(qa.w)*blo(kb.w) + bhi(qa.w)*bhi(kb.w);
        }
      }
      const bool v0 = (m_s[lane] != 0);
      const bool v1 = (lane < 56) && (m_s[m1i] != 0);
      float a0 = v0 ? acc0 : -INFINITY;
      float a1 = v1 ? acc1 : -INFINITY;
      float mx = fmaxf(a0, a1);
      #pragma unroll
      for (int off = 32; off; off >>= 1) mx = fmaxf(mx, __shfl_xor(mx, off));
      float e0 = v0 ? __expf(a0 - mx) : 0.f;
      float e1 = v1 ? __expf(a1 - mx) : 0.f;
      float sm = e0 + e1;
      #pragma unroll
      for (int off = 32; off; off >>= 1) sm += __shfl_xor(sm, off);
      const float inv = (sm > 0.f) ? (1.f / sm) : 0.f;
      const float qm = (m_s[n] != 0) ? 1.f : 0.f;
      const float rn0 = r_s[n][0], rn1 = r_s[n][1], rn2 = r_s[n][2];
      float w0 = e0 * inv * qm *
                 (rn0 * r_s[lane][0] + rn1 * r_s[lane][1] + rn2 * r_s[lane][2]);
      float w1 = 0.f;
      if (lane < 56) {
        w1 = e1 * inv * qm *
             (rn0 * r_s[m1i][0] + rn1 * r_s[m1i][1] + rn2 * r_s[m1i][2]);
      }
      aw_s[wave][lane] = w0;
      aw_s[wave][lane + 64] = w1;
      __syncthreads();
      // o[n][h] for h = lane, lane+64
      float o0 = 0.f, o1 = 0.f;
      {
        const u16* va = &vT_s[lane][0];
        const u16* vb = &vT_s[lane + 64][0];
        const float* awr = &aw_s[wave][0];
        for (int m = 0; m < NNEI; m += 8) {
          const float4 wA = *(const float4*)(awr + m);
          const float4 wB = *(const float4*)(awr + m + 4);
          const uint4 ua = *(const uint4*)(va + m);
          const uint4 ub = *(const uint4*)(vb + m);
          o0 += wA.x*blo(ua.x) + wA.y*bhi(ua.x) + wA.z*blo(ua.y) + wA.w*bhi(ua.y)
             +  wB.x*blo(ua.z) + wB.y*bhi(ua.z) + wB.z*blo(ua.w) + wB.w*bhi(ua.w);
          o1 += wA.x*blo(ub.x) + wA.y*bhi(ub.x) + wA.z*blo(ub.y) + wA.w*bhi(ub.y)
             +  wB.x*blo(ub.z) + wB.y*bhi(ub.z) + wB.z*blo(ub.w) + wB.w*bhi(ub.w);
        }
      }
      q_s[n][lane] = f2bf(o0);       // o overwrites q's row (dead now)
      q_s[n][lane + 64] = f2bf(o1);
      __syncthreads();
    }

    // ---- phase 4: x = LN(residual + o @ out_w + out_b) ----
    {
      const long owbase = (long)l * (HD * ED);
      const float ob = gld<F32>(out_b, (long)l * ED + lane);
      const float g  = gld<F32>(ln_g,  (long)l * ED + lane);
      const float bb = gld<F32>(ln_b,  (long)l * ED + lane);
      for (int n = wave; n < NNEI; n += 8) {
        float acc = x_s[n][lane] + ob;
        const u16* orow = &q_s[n][0];
        for (int h = 0; h < HD; h += 8) {
          const uint4 o8 = *(const uint4*)(orow + h);
          acc += blo(o8.x) * gld<F32>(out_w, owbase + (long)(h + 0) * ED + lane);
          acc += bhi(o8.x) * gld<F32>(out_w, owbase + (long)(h + 1) * ED + lane);
          acc += blo(o8.y) * gld<F32>(out_w, owbase + (long)(h + 2) * ED + lane);
          acc += bhi(o8.y) * gld<F32>(out_w, owbase + (long)(h + 3) * ED + lane);
          acc += blo(o8.z) * gld<F32>(out_w, owbase + (long)(h + 4) * ED + lane);
          acc += bhi(o8.z) * gld<F32>(out_w, owbase + (long)(h + 5) * ED + lane);
          acc += blo(o8.w) * gld<F32>(out_w, owbase + (long)(h + 6) * ED + lane);
          acc += bhi(o8.w) * gld<F32>(out_w, owbase + (long)(h + 7) * ED + lane);
        }
        float mu = acc;
        #pragma unroll
        for (int off = 32; off; off >>= 1) mu += __shfl_xor(mu, off);
        mu *= (1.f / 64.f);
        const float d = acc - mu;
        float var = d * d;
        #pragma unroll
        for (int off = 32; off; off >>= 1) var += __shfl_xor(var, off);
        var *= (1.f / 64.f);
        const float y = d * rsqrtf(var + LN_EPS) * g + bb;
        x_s[n][lane] = y;
        if (l == LAYERS - 1) {
          const long oidx = (long)b * (NNEI * ED) + n * ED + lane;
          if constexpr (F32) ((float*)out)[oidx] = y;
          else               ((u16*)out)[oidx] = f2bf(y);
        }
      }
    }
    __syncthreads();
  }
}

extern "C" void kernel_launch(void* const* d_in, const int* in_sizes, int n_in,
                              void* d_out, int out_size, void* d_ws, size_t ws_size,
                              hipStream_t stream) {
  (void)in_sizes; (void)n_in; (void)out_size; (void)ws_size;
  const void* G = d_in[0];
  const void* mask = d_in[1];
  const void* rr = d_in[2];
  const void* in_w = d_in[3];
  const void* in_b = d_in[4];
  const void* out_w = d_in[5];
  const void* out_b = d_in[6];
  const void* ln_g = d_in[7];
  const void* ln_b = d_in[8];
  int* flags = (int*)d_ws;

  detect_kernel<<<dim3(1), dim3(64), 0, stream>>>((const u16*)G, (const u8*)mask, flags);

  nwa_kernel<false, false><<<dim3(NB), dim3(T), 0, stream>>>(
      G, mask, rr, in_w, in_b, out_w, out_b, ln_g, ln_b, d_out, flags);
  nwa_kernel<false, true><<<dim3(NB), dim3(T), 0, stream>>>(
      G, mask, rr, in_w, in_b, out_w, out_b, ln_g, ln_b, d_out, flags);
  nwa_kernel<true, false><<<dim3(NB), dim3(T), 0, stream>>>(
      G, mask, rr, in_w, in_b, out_w, out_b, ln_g, ln_b, d_out, flags);
  nwa_kernel<true, true><<<dim3(NB), dim3(T), 0, stream>>>(
      G, mask, rr, in_w, in_b, out_w, out_b, ln_g, ln_b, d_out, flags);
}